// Round 7
// baseline (396.242 us; speedup 1.0000x reference)
//
#include <hip/hip_runtime.h>
#include <hip/hip_bf16.h>

// ---------------------------------------------------------------------------
// CCAMemoryModel forward, f32 throughout.
//  k_proj2 : per-image tiled GEMM proj (mean-shift+BN+ReLU+L2norm);
//            block 72 composes Winograd-transformed K1w.
//  k_corr  : per (b,n) 100x100x64 GEMM -> corr[bn][m][bpos].
//  k_cca   : 2 waves/block; wave = one (bn, wm, mr-half) strip.
//            Async-staged ring prefetch (issue regs -> commit LDS next iter),
//            precomputed offsets, 3-slot rings, Winograd F(2,3) h-pass,
//            g1 base-conv via in-wave shuffles. One barrier total.
//  k_msoft2: fused g2 mem-conv (w2b) + gaussian-normalize + softmax over mem
//            + sum over base -> attn_memory.
//  k_attmem: att_mem[b,n,c]
//  k_final : enc (fused) + cosine weights + softmax + mem_vec + linear head
// ---------------------------------------------------------------------------

// Blocks 0..71: proj per image. Block 72: Winograd filter transform K1w.
__global__ __launch_bounds__(512) void k_proj2(const float* __restrict__ feat_b,
                                               const float* __restrict__ feat_m,
                                               const float* __restrict__ w1x1,
                                               const float* __restrict__ gamma,
                                               const float* __restrict__ beta,
                                               const float* __restrict__ w1a,
                                               const float* __restrict__ w1b,
                                               float* __restrict__ K1w,
                                               float* __restrict__ fbp,
                                               float* __restrict__ fmp) {
    __shared__ __align__(16) float xt[64][104];   // c-tile of x; reused as zbuf
    __shared__ __align__(16) float wt[64][68];    // c-tile of w1x1
    __shared__ float colsum[100];
    __shared__ float wsumL[64];
    __shared__ float invL[100];
    const int tid = threadIdx.x;
    const int img = blockIdx.x;
    if (img == 72) {
        // K1w[(dm*3+dbh)*64 + j*16 + c], j = Winograd coeff 0..3 over dbw.
        for (int t = tid; t < 432; t += 512) {
            int tap = t >> 4, c = t & 15;
            int dm = tap / 3, dbh = tap % 3;
            float g0 = 0.f, g1 = 0.f, g2 = 0.f;
            for (int cp = 0; cp < 16; ++cp) {
                float wb = w1b[(c * 16 + cp) * 9 + dm];
                g0 = fmaf(wb, w1a[cp * 9 + dbh * 3 + 0], g0);
                g1 = fmaf(wb, w1a[cp * 9 + dbh * 3 + 1], g1);
                g2 = fmaf(wb, w1a[cp * 9 + dbh * 3 + 2], g2);
            }
            int base = tap * 64 + c;
            K1w[base]      = g0;
            K1w[base + 16] = 0.5f * (g0 + g1 + g2);
            K1w[base + 32] = 0.5f * (g0 - g1 + g2);
            K1w[base + 48] = g2;
        }
        return;
    }
    const float* x;
    float* outp;
    if (img < 8) { x = feat_b + (size_t)img * 51200; outp = fbp + (size_t)img * 6400; }
    else         { x = feat_m + (size_t)(img - 8) * 51200; outp = fmp + (size_t)(img - 8) * 6400; }

    if (tid < 100) colsum[tid] = 0.f;
    if (tid < 64) wsumL[tid] = 0.f;
    const int r = tid >> 3, q = tid & 7;   // r: out-channel, q: hw-strip
    float acc[13];
#pragma unroll
    for (int j = 0; j < 13; ++j) acc[j] = 0.f;
    __syncthreads();

    for (int ct = 0; ct < 8; ++ct) {
        for (int i = tid; i < 1600; i += 512) {
            int row = i / 25, c4 = (i % 25) * 4;
            *(float4*)&xt[row][c4] = *(const float4*)&x[(size_t)(ct * 64 + row) * 100 + c4];
        }
        for (int i = tid; i < 1024; i += 512) {
            int row = i / 16, c4 = (i % 16) * 4;
            *(float4*)&wt[row][c4] = *(const float4*)&w1x1[(size_t)row * 512 + ct * 64 + c4];
        }
        __syncthreads();
        if (tid < 100) {
            float s = 0.f;
            for (int c = 0; c < 64; ++c) s += xt[c][tid];
            colsum[tid] += s;
        }
        if (tid < 64) {
            float s = 0.f;
            for (int c = 0; c < 64; ++c) s += wt[tid][c];
            wsumL[tid] += s;
        }
        for (int c = 0; c < 64; ++c) {
            float w = wt[r][c];
#pragma unroll
            for (int j = 0; j < 13; ++j) {
                int hw = q + 8 * j;
                if (hw < 100) acc[j] = fmaf(w, xt[c][hw], acc[j]);
            }
        }
        __syncthreads();
    }
    float g = gamma[r], be = beta[r], wsr = wsumL[r];
#pragma unroll
    for (int j = 0; j < 13; ++j) {
        int hw = q + 8 * j;
        if (hw < 100) {
            float mean = colsum[hw] * (1.f / 512.f);
            xt[r][hw] = fmaxf((acc[j] - mean * wsr) * g + be, 0.f);
        }
    }
    __syncthreads();
    if (tid < 100) {
        float ss = 0.f;
        for (int rr = 0; rr < 64; ++rr) { float z = xt[rr][tid]; ss = fmaf(z, z, ss); }
        invL[tid] = 1.f / fmaxf(sqrtf(ss), 1e-8f);
    }
    __syncthreads();
    for (int i = tid; i < 6400; i += 512) {
        int rr = i / 100, hw = i % 100;
        outp[i] = xt[rr][hw] * invL[hw];
    }
}

// corr[bn][m][b] = sum_r fm[r][m]*fb[r][b]. 512 blocks.
__global__ __launch_bounds__(512) void k_corr(const float* __restrict__ fbp,
                                              const float* __restrict__ fmp,
                                              float* __restrict__ corr) {
    __shared__ __align__(16) float A[6400];
    __shared__ __align__(16) float B[6400];
    const int tid = threadIdx.x, bn = blockIdx.x;
    const float* fm = fmp + (size_t)(bn & 63) * 6400;
    const float* fb = fbp + (size_t)(bn >> 6) * 6400;
    for (int i = tid * 4; i < 6400; i += 2048) {
        *(float4*)&A[i] = *(const float4*)&fm[i];
        *(float4*)&B[i] = *(const float4*)&fb[i];
    }
    __syncthreads();
    float* dst = corr + (size_t)bn * 10000;
    for (int u = tid; u < 625; u += 512) {
        int m0 = (u / 25) * 4, b0 = (u % 25) * 4;
        float acc[4][4] = {};
        for (int r = 0; r < 64; ++r) {
            float4 av = *(const float4*)&A[r * 100 + m0];
            float4 bv = *(const float4*)&B[r * 100 + b0];
            float a[4] = {av.x, av.y, av.z, av.w};
            float bb[4] = {bv.x, bv.y, bv.z, bv.w};
#pragma unroll
            for (int i = 0; i < 4; ++i)
#pragma unroll
                for (int j = 0; j < 4; ++j) acc[i][j] = fmaf(a[i], bb[j], acc[i][j]);
        }
#pragma unroll
        for (int i = 0; i < 4; ++i)
#pragma unroll
            for (int j = 0; j < 4; ++j) dst[(m0 + i) * 100 + (b0 + j)] = acc[i][j];
    }
}

// 2 waves/block: wave = (wm, bn, half). grid (10, 512), block 128.
// Per-wave ring: 3 slots x [3 mcols][12 rows][14 cols] = 1512 f32.
// Shared zero slab 168 f32. Async staging: issue loads -> commit next iter.
__global__ __launch_bounds__(128, 5) void k_cca(const float* __restrict__ corr,
                                                const float* __restrict__ K1w,
                                                const float* __restrict__ w2a,
                                                float* __restrict__ g1out) {
    __shared__ float ringAll[2][1512];
    __shared__ float zslab[168];
    const int tid = threadIdx.x;
    const int lane = tid & 63;
    const int half = tid >> 6;
    const int wm = blockIdx.x, bn = blockIdx.y;
    const int mr_lo = half * 5;
    const int r0 = half ? 4 : 0;       // first fetched corr row
    const int Rmax = half ? 9 : 5;     // last fetched corr row
    float* ring = ringAll[half];

    for (int i = tid; i < 3024; i += 128) (&ringAll[0][0])[i] = 0.f;
    for (int i = tid; i < 168; i += 128) zslab[i] = 0.f;

    const int u = lane < 50 ? lane : 49;   // clamp spare lanes
    const int bh = u / 5, p = u % 5, bw0 = 2 * p;
    const bool act = lane < 50;

    // precomputed prefetch mapping: 5 chunks of 64 lanes cover 300 elems
    int dstoff[5], srcoff[5];
    bool val[5];
    {
        const int i0 = (wm == 0) ? 100 : 0;
        const int i1 = (wm == 9) ? 200 : 300;
#pragma unroll
        for (int k = 0; k < 5; ++k) {
            int i = lane + k * 64;
            val[k] = (i >= i0 && i < i1);
            int mc = i / 100, t = i % 100;
            dstoff[k] = mc * 168 + (t / 10 + 1) * 14 + (t % 10 + 1);
            srcoff[k] = i;
        }
    }
    const float* cbase = corr + (size_t)bn * 10000 + (wm - 1) * 100;
    __syncthreads();   // zslab + ring halos zeroed (both waves write both rings)

    float pv[5];
    auto issueRow = [&](int R) {
#pragma unroll
        for (int k = 0; k < 5; ++k) {
            float v = 0.f;
            if (val[k]) v = cbase[R * 1000 + srcoff[k]];
            pv[k] = v;
        }
    };
    auto commitRow = [&](int R) {
        int sb = (R % 3) * 504;
#pragma unroll
        for (int k = 0; k < 5; ++k)
            if (val[k]) ring[sb + dstoff[k]] = pv[k];
    };

    issueRow(r0);     commitRow(r0);
    issueRow(r0 + 1); commitRow(r0 + 1);
    issueRow(r0 + 2);  // in flight; committed at top of first iter

    const int rbase = bh * 14 + bw0;
#pragma unroll
    for (int j = 0; j < 5; ++j) {
        const int mr = mr_lo + j;
        { int R = r0 + 2 + j; if (R <= Rmax) commitRow(R); }   // waits 1-iter-old loads
        { int R = r0 + 3 + j; if (R <= Rmax) issueRow(R); }    // flies under compute

        // ---- h pass: Winograd F(2,3) over bw, 4 accumulator banks ----
        float A1[16], A2[16], A3[16], A4[16];
#pragma unroll
        for (int c = 0; c < 16; ++c) { A1[c] = 0.f; A2[c] = 0.f; A3[c] = 0.f; A4[c] = 0.f; }
        for (int dmh = 0; dmh < 3; ++dmh) {
            int mrow = mr + dmh - 1;
            if ((unsigned)mrow >= 10u) continue;
            const float* slab0 = &ring[(mrow % 3) * 504];
#pragma unroll
            for (int dmw = 0; dmw < 3; ++dmw) {
                bool mv = (unsigned)(wm + dmw - 1) < 10u;
                const float* cb = (mv ? slab0 + dmw * 168 : zslab) + rbase;
                const float* kp = K1w + (dmh * 3 + dmw) * 192;
#pragma unroll
                for (int dbh = 0; dbh < 3; ++dbh) {
                    float2 lo = *(const float2*)&cb[dbh * 14];
                    float2 hi = *(const float2*)&cb[dbh * 14 + 2];
                    float t1 = lo.x - hi.x;
                    float t2 = lo.y + hi.x;
                    float t3 = hi.x - lo.y;
                    float t4 = lo.y - hi.y;
                    const float* kq = kp + dbh * 64;
#pragma unroll
                    for (int c = 0; c < 16; ++c) {
                        A1[c] = fmaf(t1, kq[c], A1[c]);
                        A2[c] = fmaf(t2, kq[16 + c], A2[c]);
                        A3[c] = fmaf(t3, kq[32 + c], A3[c]);
                        A4[c] = fmaf(t4, kq[48 + c], A4[c]);
                    }
                }
            }
        }

        // ---- g1 base-conv via in-wave shuffles (partial row sums) ----
        float P00 = 0.f, P01 = 0.f, P10 = 0.f, P11 = 0.f, P20 = 0.f, P21 = 0.f;
#pragma unroll
        for (int c = 0; c < 16; ++c) {
            float rr0 = fmaxf(A1[c] + A2[c] + A3[c], 0.f);
            float rr1 = fmaxf(A2[c] - A3[c] - A4[c], 0.f);
            float lA = __shfl(rr1, lane - 1); lA = (p > 0) ? lA : 0.f;   // col bw0-1
            float rA = __shfl(rr0, lane + 1); rA = (p < 4) ? rA : 0.f;   // col bw0+2
            const float* wq = w2a + c * 9;
            P00 = fmaf(wq[0], lA, fmaf(wq[1], rr0, fmaf(wq[2], rr1, P00)));
            P01 = fmaf(wq[0], rr0, fmaf(wq[1], rr1, fmaf(wq[2], rA, P01)));
            P10 = fmaf(wq[3], lA, fmaf(wq[4], rr0, fmaf(wq[5], rr1, P10)));
            P11 = fmaf(wq[3], rr0, fmaf(wq[4], rr1, fmaf(wq[5], rA, P11)));
            P20 = fmaf(wq[6], lA, fmaf(wq[7], rr0, fmaf(wq[8], rr1, P20)));
            P21 = fmaf(wq[6], rr0, fmaf(wq[7], rr1, fmaf(wq[8], rA, P21)));
        }
        // out row bh takes: P0 from row bh-1 (lane-5), own P1, P2 from row bh+1.
        float u00 = __shfl(P00, lane - 5), u01 = __shfl(P01, lane - 5);
        float u20 = __shfl(P20, lane + 5), u21 = __shfl(P21, lane + 5);
        if (bh == 0) { u00 = 0.f; u01 = 0.f; }
        if (bh == 9) { u20 = 0.f; u21 = 0.f; }
        float g0 = P10 + u00 + u20;
        float g1v = P11 + u01 + u21;
        if (act) {
            float2 st; st.x = g0; st.y = g1v;
            *(float2*)&g1out[(size_t)bn * 10000 + (mr * 10 + wm) * 100 + bh * 10 + bw0] = st;
        }
    }
}

// Fused g2 (w2b mem-conv) + gaussian-normalize over mem + softmax + sum over
// base. One block per bn (512 x 512 thr).
__global__ __launch_bounds__(512) void k_msoft2(const float* __restrict__ g1,
                                                const float* __restrict__ w2b,
                                                float* __restrict__ attnm) {
    __shared__ float gt[10000];
    const int tid = threadIdx.x, bn = blockIdx.x;
    const float* src = g1 + (size_t)bn * 10000;
    for (int i = tid; i < 10000; i += 512) gt[i] = src[i];
    __syncthreads();
    float wb[9];
#pragma unroll
    for (int t = 0; t < 9; ++t) wb[t] = w2b[t];
    const int b = tid >> 2, q = tid & 3;
    const bool act = tid < 400;
    float ev[25];
    float se = 0.f;
    if (act) {
        float s = 0.f, ss = 0.f;
#pragma unroll
        for (int i = 0; i < 25; ++i) {
            int m = q * 25 + i, mh = m / 10, mw = m % 10;
            float v = 0.f;
#pragma unroll
            for (int dh = 0; dh < 3; ++dh) {
                int rr = mh + dh - 1;
                if ((unsigned)rr < 10u) {
#pragma unroll
                    for (int dw = 0; dw < 3; ++dw) {
                        int ww = mw + dw - 1;
                        if ((unsigned)ww < 10u)
                            v = fmaf(wb[dh * 3 + dw], gt[(rr * 10 + ww) * 100 + b], v);
                    }
                }
            }
            ev[i] = v;
            s += v; ss = fmaf(v, v, ss);
        }
        s += __shfl_xor(s, 1); s += __shfl_xor(s, 2);
        ss += __shfl_xor(ss, 1); ss += __shfl_xor(ss, 2);
        float mean = s * 0.01f;
        float var = (ss - 100.f * mean * mean) * (1.f / 99.f);
        float istd = 0.2f / sqrtf(var + 1e-5f);  // includes 1/TEMP
        float mx = -1e30f;
#pragma unroll
        for (int i = 0; i < 25; ++i) mx = fmaxf(mx, ev[i]);
        mx = fmaxf(mx, __shfl_xor(mx, 1)); mx = fmaxf(mx, __shfl_xor(mx, 2));
#pragma unroll
        for (int i = 0; i < 25; ++i) {
            float e = expf((ev[i] - mx) * istd);
            ev[i] = e; se += e;
        }
        se += __shfl_xor(se, 1); se += __shfl_xor(se, 2);
    }
    __syncthreads();   // all conv reads of gt done
    if (act) {
        float inv = 1.f / se;
#pragma unroll
        for (int i = 0; i < 25; ++i) gt[(q * 25 + i) * 100 + b] = ev[i] * inv;
    }
    __syncthreads();
    if (act) {
        int m = tid >> 2;
        float s2 = 0.f;
#pragma unroll
        for (int i = 0; i < 25; ++i) s2 += gt[m * 100 + q * 25 + i];
        s2 += __shfl_xor(s2, 1); s2 += __shfl_xor(s2, 2);
        if (q == 0) attnm[bn * 100 + m] = s2;
    }
}

// grid (64 n, 4 c-chunks), block 128.
__global__ __launch_bounds__(128) void k_attmem(const float* __restrict__ attnm,
                                                const float* __restrict__ feat_m,
                                                float* __restrict__ attm) {
    __shared__ float A[8][100];
    int n = blockIdx.x, cq = blockIdx.y, tid = threadIdx.x;
    for (int i = tid; i < 800; i += 128) {
        int b = i / 100, m = i % 100;
        A[b][m] = attnm[(b * 64 + n) * 100 + m];
    }
    __syncthreads();
    int c = cq * 128 + tid;
    const float* fp = feat_m + ((size_t)n * 512 + c) * 100;
    float acc[8] = {};
    for (int m4 = 0; m4 < 100; m4 += 4) {
        float4 v = *(const float4*)&fp[m4];
#pragma unroll
        for (int b = 0; b < 8; ++b) {
            acc[b] = fmaf(A[b][m4], v.x, acc[b]);
            acc[b] = fmaf(A[b][m4 + 1], v.y, acc[b]);
            acc[b] = fmaf(A[b][m4 + 2], v.z, acc[b]);
            acc[b] = fmaf(A[b][m4 + 3], v.w, acc[b]);
        }
    }
#pragma unroll
    for (int b = 0; b < 8; ++b)
        attm[((size_t)(b * 64 + n)) * 512 + c] = acc[b] * 0.01f;
}

// Fused enc + memory-wrap head. One block per b (8 blocks, 512 threads).
__global__ __launch_bounds__(512) void k_final(const float* __restrict__ feat_b,
                                               const float* __restrict__ attm,
                                               const float* __restrict__ w_fc,
                                               const float* __restrict__ b_fc,
                                               float* __restrict__ out) {
    __shared__ float attL[64 * 513];
    __shared__ float encL[512];
    __shared__ float mv[512];
    __shared__ float wL[64];
    __shared__ float red[512];
    int b = blockIdx.x, tid = threadIdx.x;
    {
        const float* fp = feat_b + ((size_t)b * 512 + tid) * 100;
        float s = 0.f;
        for (int m = 0; m < 100; m += 4) {
            float4 v = *(const float4*)&fp[m];
            s += v.x + v.y + v.z + v.w;
        }
        float e = s * 0.01f;
        encL[tid] = e;
        red[tid] = e * e;
    }
    const float* ap = attm + (size_t)b * 32768;
    for (int i = tid; i < 32768; i += 512) attL[(i >> 9) * 513 + (i & 511)] = ap[i];
    __syncthreads();
    for (int o = 256; o; o >>= 1) {
        if (tid < o) red[tid] += red[tid + o];
        __syncthreads();
    }
    float escale = 1.f / fmaxf(sqrtf(red[0]), 1e-8f);
    if (tid < 64) {
        int n = tid;
        float ss = 0.f, dp = 0.f;
        for (int c = 0; c < 512; ++c) {
            float a = attL[n * 513 + c];
            ss = fmaf(a, a, ss);
            dp = fmaf(encL[c], a, dp);
        }
        float sc = dp * escale / fmaxf(sqrtf(ss), 1e-8f);
        float mx = sc;
#pragma unroll
        for (int o = 32; o; o >>= 1) mx = fmaxf(mx, __shfl_xor(mx, o));
        float e = expf(sc - mx);
        float seL = e;
#pragma unroll
        for (int o = 32; o; o >>= 1) seL += __shfl_xor(seL, o);
        wL[n] = e / seL;
    }
    __syncthreads();
    {
        int c = tid;
        float s = 0.f;
        for (int n = 0; n < 64; ++n) s = fmaf(wL[n], attL[n * 513 + c], s);
        mv[c] = s;
    }
    __syncthreads();
    for (int k = tid; k < 100; k += 512) {
        const float* wp = w_fc + (size_t)k * 1024;
        float acc = b_fc[k];
        for (int c = 0; c < 512; c += 4) {
            float4 w0 = *(const float4*)&wp[c];
            float4 w1 = *(const float4*)&wp[512 + c];
            acc = fmaf(encL[c], w0.x, acc);     acc = fmaf(encL[c + 1], w0.y, acc);
            acc = fmaf(encL[c + 2], w0.z, acc); acc = fmaf(encL[c + 3], w0.w, acc);
            acc = fmaf(mv[c], w1.x, acc);       acc = fmaf(mv[c + 1], w1.y, acc);
            acc = fmaf(mv[c + 2], w1.z, acc);   acc = fmaf(mv[c + 3], w1.w, acc);
        }
        out[b * 100 + k] = acc;
    }
}

extern "C" void kernel_launch(void* const* d_in, const int* in_sizes, int n_in,
                              void* d_out, int out_size, void* d_ws, size_t ws_size,
                              hipStream_t stream) {
    const float* feat_b = (const float*)d_in[0];
    const float* feat_m = (const float*)d_in[1];
    const float* w1x1   = (const float*)d_in[2];
    const float* gamma  = (const float*)d_in[3];
    const float* beta   = (const float*)d_in[4];
    const float* w1a    = (const float*)d_in[5];
    const float* w1b    = (const float*)d_in[6];
    const float* w2a    = (const float*)d_in[7];
    const float* w2b    = (const float*)d_in[8];
    const float* w_fc   = (const float*)d_in[9];
    const float* b_fc   = (const float*)d_in[10];

    float* ws    = (float*)d_ws;
    float* K1w   = ws;                     // 1728 (pad 1760)
    float* fbp   = ws + 1760;              // 51200
    float* fmp   = fbp + 51200;            // 409600
    float* corr  = fmp + 409600;           // 5120000
    float* g1    = corr + 5120000;         // 5120000
    float* attnm = g1 + 5120000;           // 51200
    float* attm  = attnm + 51200;          // 262144

    hipLaunchKernelGGL(k_proj2, dim3(73), dim3(512), 0, stream,
                       feat_b, feat_m, w1x1, gamma, beta, w1a, w1b, K1w, fbp, fmp);
    hipLaunchKernelGGL(k_corr, dim3(512), dim3(512), 0, stream, fbp, fmp, corr);
    hipLaunchKernelGGL(k_cca, dim3(10, 512), dim3(128), 0, stream,
                       corr, K1w, w2a, g1);
    hipLaunchKernelGGL(k_msoft2, dim3(512), dim3(512), 0, stream, g1, w2b, attnm);
    hipLaunchKernelGGL(k_attmem, dim3(64, 4), dim3(128), 0, stream, attnm, feat_m, attm);
    hipLaunchKernelGGL(k_final, dim3(8), dim3(512), 0, stream,
                       feat_b, attm, w_fc, b_fc, (float*)d_out);
}

// Round 8
// 312.873 us; speedup vs baseline: 1.2665x; 1.2665x over previous
//
#include <hip/hip_runtime.h>
#include <hip/hip_bf16.h>

// ---------------------------------------------------------------------------
// CCAMemoryModel forward, f32 throughout.
//  k_proj2 : per-image tiled GEMM proj (mean-shift+BN+ReLU+L2norm);
//            block 72 composes Winograd-transformed K1w.
//  k_corr  : per (b,n) 100x100x64 GEMM -> corr[bn][m][bpos].
//  k_cca   : 2 waves/block, wave = (wm, bn, mr-half) strip (different bn per
//            wave). 3-slot ring w/ safe fetch-(mr+1)-at-top schedule,
//            Winograd F(2,3) h-pass, g1 base-conv via in-wave shuffles.
//            One barrier total (init). 12.8 KB LDS -> 12 blocks/CU.
//  k_msoft2: fused g2 mem-conv (w2b) + gaussian-normalize + softmax over mem
//            + sum over base -> attn_memory.
//  k_attmem: att_mem[b,n,c]
//  k_final : enc (fused) + cosine weights + softmax + mem_vec + linear head
// ---------------------------------------------------------------------------

// Blocks 0..71: proj per image. Block 72: Winograd filter transform K1w.
__global__ __launch_bounds__(512) void k_proj2(const float* __restrict__ feat_b,
                                               const float* __restrict__ feat_m,
                                               const float* __restrict__ w1x1,
                                               const float* __restrict__ gamma,
                                               const float* __restrict__ beta,
                                               const float* __restrict__ w1a,
                                               const float* __restrict__ w1b,
                                               float* __restrict__ K1w,
                                               float* __restrict__ fbp,
                                               float* __restrict__ fmp) {
    __shared__ __align__(16) float xt[64][104];   // c-tile of x; reused as zbuf
    __shared__ __align__(16) float wt[64][68];    // c-tile of w1x1
    __shared__ float colsum[100];
    __shared__ float wsumL[64];
    __shared__ float invL[100];
    const int tid = threadIdx.x;
    const int img = blockIdx.x;
    if (img == 72) {
        // K1w[(dm*3+dbh)*64 + j*16 + c], j = Winograd coeff 0..3 over dbw.
        for (int t = tid; t < 432; t += 512) {
            int tap = t >> 4, c = t & 15;
            int dm = tap / 3, dbh = tap % 3;
            float g0 = 0.f, g1 = 0.f, g2 = 0.f;
            for (int cp = 0; cp < 16; ++cp) {
                float wb = w1b[(c * 16 + cp) * 9 + dm];
                g0 = fmaf(wb, w1a[cp * 9 + dbh * 3 + 0], g0);
                g1 = fmaf(wb, w1a[cp * 9 + dbh * 3 + 1], g1);
                g2 = fmaf(wb, w1a[cp * 9 + dbh * 3 + 2], g2);
            }
            int base = tap * 64 + c;
            K1w[base]      = g0;
            K1w[base + 16] = 0.5f * (g0 + g1 + g2);
            K1w[base + 32] = 0.5f * (g0 - g1 + g2);
            K1w[base + 48] = g2;
        }
        return;
    }
    const float* x;
    float* outp;
    if (img < 8) { x = feat_b + (size_t)img * 51200; outp = fbp + (size_t)img * 6400; }
    else         { x = feat_m + (size_t)(img - 8) * 51200; outp = fmp + (size_t)(img - 8) * 6400; }

    if (tid < 100) colsum[tid] = 0.f;
    if (tid < 64) wsumL[tid] = 0.f;
    const int r = tid >> 3, q = tid & 7;   // r: out-channel, q: hw-strip
    float acc[13];
#pragma unroll
    for (int j = 0; j < 13; ++j) acc[j] = 0.f;
    __syncthreads();

    for (int ct = 0; ct < 8; ++ct) {
        for (int i = tid; i < 1600; i += 512) {
            int row = i / 25, c4 = (i % 25) * 4;
            *(float4*)&xt[row][c4] = *(const float4*)&x[(size_t)(ct * 64 + row) * 100 + c4];
        }
        for (int i = tid; i < 1024; i += 512) {
            int row = i / 16, c4 = (i % 16) * 4;
            *(float4*)&wt[row][c4] = *(const float4*)&w1x1[(size_t)row * 512 + ct * 64 + c4];
        }
        __syncthreads();
        if (tid < 100) {
            float s = 0.f;
            for (int c = 0; c < 64; ++c) s += xt[c][tid];
            colsum[tid] += s;
        }
        if (tid < 64) {
            float s = 0.f;
            for (int c = 0; c < 64; ++c) s += wt[tid][c];
            wsumL[tid] += s;
        }
        for (int c = 0; c < 64; ++c) {
            float w = wt[r][c];
#pragma unroll
            for (int j = 0; j < 13; ++j) {
                int hw = q + 8 * j;
                if (hw < 100) acc[j] = fmaf(w, xt[c][hw], acc[j]);
            }
        }
        __syncthreads();
    }
    float g = gamma[r], be = beta[r], wsr = wsumL[r];
#pragma unroll
    for (int j = 0; j < 13; ++j) {
        int hw = q + 8 * j;
        if (hw < 100) {
            float mean = colsum[hw] * (1.f / 512.f);
            xt[r][hw] = fmaxf((acc[j] - mean * wsr) * g + be, 0.f);
        }
    }
    __syncthreads();
    if (tid < 100) {
        float ss = 0.f;
        for (int rr = 0; rr < 64; ++rr) { float z = xt[rr][tid]; ss = fmaf(z, z, ss); }
        invL[tid] = 1.f / fmaxf(sqrtf(ss), 1e-8f);
    }
    __syncthreads();
    for (int i = tid; i < 6400; i += 512) {
        int rr = i / 100, hw = i % 100;
        outp[i] = xt[rr][hw] * invL[hw];
    }
}

// corr[bn][m][b] = sum_r fm[r][m]*fb[r][b]. 512 blocks.
__global__ __launch_bounds__(512) void k_corr(const float* __restrict__ fbp,
                                              const float* __restrict__ fmp,
                                              float* __restrict__ corr) {
    __shared__ __align__(16) float A[6400];
    __shared__ __align__(16) float B[6400];
    const int tid = threadIdx.x, bn = blockIdx.x;
    const float* fm = fmp + (size_t)(bn & 63) * 6400;
    const float* fb = fbp + (size_t)(bn >> 6) * 6400;
    for (int i = tid * 4; i < 6400; i += 2048) {
        *(float4*)&A[i] = *(const float4*)&fm[i];
        *(float4*)&B[i] = *(const float4*)&fb[i];
    }
    __syncthreads();
    float* dst = corr + (size_t)bn * 10000;
    for (int u = tid; u < 625; u += 512) {
        int m0 = (u / 25) * 4, b0 = (u % 25) * 4;
        float acc[4][4] = {};
        for (int r = 0; r < 64; ++r) {
            float4 av = *(const float4*)&A[r * 100 + m0];
            float4 bv = *(const float4*)&B[r * 100 + b0];
            float a[4] = {av.x, av.y, av.z, av.w};
            float bb[4] = {bv.x, bv.y, bv.z, bv.w};
#pragma unroll
            for (int i = 0; i < 4; ++i)
#pragma unroll
                for (int j = 0; j < 4; ++j) acc[i][j] = fmaf(a[i], bb[j], acc[i][j]);
        }
#pragma unroll
        for (int i = 0; i < 4; ++i)
#pragma unroll
            for (int j = 0; j < 4; ++j) dst[(m0 + i) * 100 + (b0 + j)] = acc[i][j];
    }
}

// 2 waves/block, wave = (wm, bn = 2*by+wv, half). grid (10, 256, 2), block 128.
// Per-wave ring: 3 slots x [3 mcols][12 rows][14 cols] = 1512 f32; shared
// zero slab 168 f32. Safe schedule: iter mr fetches row mr+1 into slot
// (mr+1)%3 (previously row mr-2, dead). Single-wave in-order DS -> no
// barriers inside the loop.
__global__ __launch_bounds__(128, 4) void k_cca(const float* __restrict__ corr,
                                                const float* __restrict__ K1w,
                                                const float* __restrict__ w2a,
                                                float* __restrict__ g1out) {
    __shared__ float ringAll[2][1512];
    __shared__ float zslab[168];
    const int tid = threadIdx.x;
    const int lane = tid & 63;
    const int wv = tid >> 6;
    const int wm = blockIdx.x;
    const int bn = blockIdx.y * 2 + wv;
    const int half = blockIdx.z;
    const int mr_lo = half * 5;
    const int Rmax = half ? 9 : 5;
    float* ring = ringAll[wv];

    for (int i = lane; i < 1512; i += 64) ring[i] = 0.f;
    for (int i = tid; i < 168; i += 128) zslab[i] = 0.f;

    const int u = lane < 50 ? lane : 49;   // clamp spare lanes
    const int bh = u / 5, p = u % 5, bw0 = 2 * p;
    const bool act = lane < 50;

    const float* cbase = corr + (size_t)bn * 10000 + (wm - 1) * 100;
    const int i0 = (wm == 0) ? 100 : 0;
    const int i1 = (wm == 9) ? 200 : 300;

    auto prefetch = [&](int R) {
        const float* src = cbase + R * 1000;
        float* dslot = &ring[(R % 3) * 504];
#pragma unroll
        for (int k = 0; k < 5; ++k) {
            int i = lane + k * 64;
            if (i >= i0 && i < i1) {
                int mc = i / 100, t = i % 100;
                dslot[mc * 168 + (t / 10 + 1) * 14 + (t % 10 + 1)] = src[i];
            }
        }
    };
    __syncthreads();   // zslab zeroed (written by both waves)

    if (mr_lo > 0) prefetch(mr_lo - 1);
    prefetch(mr_lo);

    const int rbase = bh * 14 + bw0;
#pragma unroll
    for (int j = 0; j < 5; ++j) {
        const int mr = mr_lo + j;
        if (mr + 1 <= Rmax) prefetch(mr + 1);   // slot (mr+1)%3: row mr-2, dead

        // ---- h pass: Winograd F(2,3) over bw, 4 accumulator banks ----
        float A1[16], A2[16], A3[16], A4[16];
#pragma unroll
        for (int c = 0; c < 16; ++c) { A1[c] = 0.f; A2[c] = 0.f; A3[c] = 0.f; A4[c] = 0.f; }
        for (int dmh = 0; dmh < 3; ++dmh) {
            int mrow = mr + dmh - 1;
            if ((unsigned)mrow >= 10u) continue;
            const float* slab0 = &ring[(mrow % 3) * 504];
#pragma unroll
            for (int dmw = 0; dmw < 3; ++dmw) {
                bool mv = (unsigned)(wm + dmw - 1) < 10u;
                const float* cb = (mv ? slab0 + dmw * 168 : zslab) + rbase;
                const float* kp = K1w + (dmh * 3 + dmw) * 192;
#pragma unroll
                for (int dbh = 0; dbh < 3; ++dbh) {
                    float2 lo = *(const float2*)&cb[dbh * 14];
                    float2 hi = *(const float2*)&cb[dbh * 14 + 2];
                    float t1 = lo.x - hi.x;
                    float t2 = lo.y + hi.x;
                    float t3 = hi.x - lo.y;
                    float t4 = lo.y - hi.y;
                    const float* kq = kp + dbh * 64;
#pragma unroll
                    for (int c = 0; c < 16; ++c) {
                        A1[c] = fmaf(t1, kq[c], A1[c]);
                        A2[c] = fmaf(t2, kq[16 + c], A2[c]);
                        A3[c] = fmaf(t3, kq[32 + c], A3[c]);
                        A4[c] = fmaf(t4, kq[48 + c], A4[c]);
                    }
                }
            }
        }

        // ---- g1 base-conv via in-wave shuffles (partial row sums) ----
        float P00 = 0.f, P01 = 0.f, P10 = 0.f, P11 = 0.f, P20 = 0.f, P21 = 0.f;
#pragma unroll
        for (int c = 0; c < 16; ++c) {
            float rr0 = fmaxf(A1[c] + A2[c] + A3[c], 0.f);
            float rr1 = fmaxf(A2[c] - A3[c] - A4[c], 0.f);
            float lA = __shfl(rr1, lane - 1); lA = (p > 0) ? lA : 0.f;   // col bw0-1
            float rA = __shfl(rr0, lane + 1); rA = (p < 4) ? rA : 0.f;   // col bw0+2
            const float* wq = w2a + c * 9;
            P00 = fmaf(wq[0], lA, fmaf(wq[1], rr0, fmaf(wq[2], rr1, P00)));
            P01 = fmaf(wq[0], rr0, fmaf(wq[1], rr1, fmaf(wq[2], rA, P01)));
            P10 = fmaf(wq[3], lA, fmaf(wq[4], rr0, fmaf(wq[5], rr1, P10)));
            P11 = fmaf(wq[3], rr0, fmaf(wq[4], rr1, fmaf(wq[5], rA, P11)));
            P20 = fmaf(wq[6], lA, fmaf(wq[7], rr0, fmaf(wq[8], rr1, P20)));
            P21 = fmaf(wq[6], rr0, fmaf(wq[7], rr1, fmaf(wq[8], rA, P21)));
        }
        // out row bh takes: P0 from row bh-1 (lane-5), own P1, P2 from row bh+1.
        float u00 = __shfl(P00, lane - 5), u01 = __shfl(P01, lane - 5);
        float u20 = __shfl(P20, lane + 5), u21 = __shfl(P21, lane + 5);
        if (bh == 0) { u00 = 0.f; u01 = 0.f; }
        if (bh == 9) { u20 = 0.f; u21 = 0.f; }
        float g0 = P10 + u00 + u20;
        float g1v = P11 + u01 + u21;
        if (act) {
            float2 st; st.x = g0; st.y = g1v;
            *(float2*)&g1out[(size_t)bn * 10000 + (mr * 10 + wm) * 100 + bh * 10 + bw0] = st;
        }
    }
}

// Fused g2 (w2b mem-conv) + gaussian-normalize over mem + softmax + sum over
// base. One block per bn (512 x 512 thr).
__global__ __launch_bounds__(512) void k_msoft2(const float* __restrict__ g1,
                                                const float* __restrict__ w2b,
                                                float* __restrict__ attnm) {
    __shared__ float gt[10000];
    const int tid = threadIdx.x, bn = blockIdx.x;
    const float* src = g1 + (size_t)bn * 10000;
    for (int i = tid; i < 10000; i += 512) gt[i] = src[i];
    __syncthreads();
    float wb[9];
#pragma unroll
    for (int t = 0; t < 9; ++t) wb[t] = w2b[t];
    const int b = tid >> 2, q = tid & 3;
    const bool act = tid < 400;
    float ev[25];
    float se = 0.f;
    if (act) {
        float s = 0.f, ss = 0.f;
#pragma unroll
        for (int i = 0; i < 25; ++i) {
            int m = q * 25 + i, mh = m / 10, mw = m % 10;
            float v = 0.f;
#pragma unroll
            for (int dh = 0; dh < 3; ++dh) {
                int rr = mh + dh - 1;
                if ((unsigned)rr < 10u) {
#pragma unroll
                    for (int dw = 0; dw < 3; ++dw) {
                        int ww = mw + dw - 1;
                        if ((unsigned)ww < 10u)
                            v = fmaf(wb[dh * 3 + dw], gt[(rr * 10 + ww) * 100 + b], v);
                    }
                }
            }
            ev[i] = v;
            s += v; ss = fmaf(v, v, ss);
        }
        s += __shfl_xor(s, 1); s += __shfl_xor(s, 2);
        ss += __shfl_xor(ss, 1); ss += __shfl_xor(ss, 2);
        float mean = s * 0.01f;
        float var = (ss - 100.f * mean * mean) * (1.f / 99.f);
        float istd = 0.2f / sqrtf(var + 1e-5f);  // includes 1/TEMP
        float mx = -1e30f;
#pragma unroll
        for (int i = 0; i < 25; ++i) mx = fmaxf(mx, ev[i]);
        mx = fmaxf(mx, __shfl_xor(mx, 1)); mx = fmaxf(mx, __shfl_xor(mx, 2));
#pragma unroll
        for (int i = 0; i < 25; ++i) {
            float e = expf((ev[i] - mx) * istd);
            ev[i] = e; se += e;
        }
        se += __shfl_xor(se, 1); se += __shfl_xor(se, 2);
    }
    __syncthreads();   // all conv reads of gt done
    if (act) {
        float inv = 1.f / se;
#pragma unroll
        for (int i = 0; i < 25; ++i) gt[(q * 25 + i) * 100 + b] = ev[i] * inv;
    }
    __syncthreads();
    if (act) {
        int m = tid >> 2;
        float s2 = 0.f;
#pragma unroll
        for (int i = 0; i < 25; ++i) s2 += gt[m * 100 + q * 25 + i];
        s2 += __shfl_xor(s2, 1); s2 += __shfl_xor(s2, 2);
        if (q == 0) attnm[bn * 100 + m] = s2;
    }
}

// grid (64 n, 4 c-chunks), block 128.
__global__ __launch_bounds__(128) void k_attmem(const float* __restrict__ attnm,
                                                const float* __restrict__ feat_m,
                                                float* __restrict__ attm) {
    __shared__ float A[8][100];
    int n = blockIdx.x, cq = blockIdx.y, tid = threadIdx.x;
    for (int i = tid; i < 800; i += 128) {
        int b = i / 100, m = i % 100;
        A[b][m] = attnm[(b * 64 + n) * 100 + m];
    }
    __syncthreads();
    int c = cq * 128 + tid;
    const float* fp = feat_m + ((size_t)n * 512 + c) * 100;
    float acc[8] = {};
    for (int m4 = 0; m4 < 100; m4 += 4) {
        float4 v = *(const float4*)&fp[m4];
#pragma unroll
        for (int b = 0; b < 8; ++b) {
            acc[b] = fmaf(A[b][m4], v.x, acc[b]);
            acc[b] = fmaf(A[b][m4 + 1], v.y, acc[b]);
            acc[b] = fmaf(A[b][m4 + 2], v.z, acc[b]);
            acc[b] = fmaf(A[b][m4 + 3], v.w, acc[b]);
        }
    }
#pragma unroll
    for (int b = 0; b < 8; ++b)
        attm[((size_t)(b * 64 + n)) * 512 + c] = acc[b] * 0.01f;
}

// Fused enc + memory-wrap head. One block per b (8 blocks, 512 threads).
__global__ __launch_bounds__(512) void k_final(const float* __restrict__ feat_b,
                                               const float* __restrict__ attm,
                                               const float* __restrict__ w_fc,
                                               const float* __restrict__ b_fc,
                                               float* __restrict__ out) {
    __shared__ float attL[64 * 513];
    __shared__ float encL[512];
    __shared__ float mv[512];
    __shared__ float wL[64];
    __shared__ float red[512];
    int b = blockIdx.x, tid = threadIdx.x;
    {
        const float* fp = feat_b + ((size_t)b * 512 + tid) * 100;
        float s = 0.f;
        for (int m = 0; m < 100; m += 4) {
            float4 v = *(const float4*)&fp[m];
            s += v.x + v.y + v.z + v.w;
        }
        float e = s * 0.01f;
        encL[tid] = e;
        red[tid] = e * e;
    }
    const float* ap = attm + (size_t)b * 32768;
    for (int i = tid; i < 32768; i += 512) attL[(i >> 9) * 513 + (i & 511)] = ap[i];
    __syncthreads();
    for (int o = 256; o; o >>= 1) {
        if (tid < o) red[tid] += red[tid + o];
        __syncthreads();
    }
    float escale = 1.f / fmaxf(sqrtf(red[0]), 1e-8f);
    if (tid < 64) {
        int n = tid;
        float ss = 0.f, dp = 0.f;
        for (int c = 0; c < 512; ++c) {
            float a = attL[n * 513 + c];
            ss = fmaf(a, a, ss);
            dp = fmaf(encL[c], a, dp);
        }
        float sc = dp * escale / fmaxf(sqrtf(ss), 1e-8f);
        float mx = sc;
#pragma unroll
        for (int o = 32; o; o >>= 1) mx = fmaxf(mx, __shfl_xor(mx, o));
        float e = expf(sc - mx);
        float seL = e;
#pragma unroll
        for (int o = 32; o; o >>= 1) seL += __shfl_xor(seL, o);
        wL[n] = e / seL;
    }
    __syncthreads();
    {
        int c = tid;
        float s = 0.f;
        for (int n = 0; n < 64; ++n) s = fmaf(wL[n], attL[n * 513 + c], s);
        mv[c] = s;
    }
    __syncthreads();
    for (int k = tid; k < 100; k += 512) {
        const float* wp = w_fc + (size_t)k * 1024;
        float acc = b_fc[k];
        for (int c = 0; c < 512; c += 4) {
            float4 w0 = *(const float4*)&wp[c];
            float4 w1 = *(const float4*)&wp[512 + c];
            acc = fmaf(encL[c], w0.x, acc);     acc = fmaf(encL[c + 1], w0.y, acc);
            acc = fmaf(encL[c + 2], w0.z, acc); acc = fmaf(encL[c + 3], w0.w, acc);
            acc = fmaf(mv[c], w1.x, acc);       acc = fmaf(mv[c + 1], w1.y, acc);
            acc = fmaf(mv[c + 2], w1.z, acc);   acc = fmaf(mv[c + 3], w1.w, acc);
        }
        out[b * 100 + k] = acc;
    }
}

extern "C" void kernel_launch(void* const* d_in, const int* in_sizes, int n_in,
                              void* d_out, int out_size, void* d_ws, size_t ws_size,
                              hipStream_t stream) {
    const float* feat_b = (const float*)d_in[0];
    const float* feat_m = (const float*)d_in[1];
    const float* w1x1   = (const float*)d_in[2];
    const float* gamma  = (const float*)d_in[3];
    const float* beta   = (const float*)d_in[4];
    const float* w1a    = (const float*)d_in[5];
    const float* w1b    = (const float*)d_in[6];
    const float* w2a    = (const float*)d_in[7];
    const float* w2b    = (const float*)d_in[8];
    const float* w_fc   = (const float*)d_in[9];
    const float* b_fc   = (const float*)d_in[10];

    float* ws    = (float*)d_ws;
    float* K1w   = ws;                     // 1728 (pad 1760)
    float* fbp   = ws + 1760;              // 51200
    float* fmp   = fbp + 51200;            // 409600
    float* corr  = fmp + 409600;           // 5120000
    float* g1    = corr + 5120000;         // 5120000
    float* attnm = g1 + 5120000;           // 51200
    float* attm  = attnm + 51200;          // 262144

    hipLaunchKernelGGL(k_proj2, dim3(73), dim3(512), 0, stream,
                       feat_b, feat_m, w1x1, gamma, beta, w1a, w1b, K1w, fbp, fmp);
    hipLaunchKernelGGL(k_corr, dim3(512), dim3(512), 0, stream, fbp, fmp, corr);
    hipLaunchKernelGGL(k_cca, dim3(10, 256, 2), dim3(128), 0, stream,
                       corr, K1w, w2a, g1);
    hipLaunchKernelGGL(k_msoft2, dim3(512), dim3(512), 0, stream, g1, w2b, attnm);
    hipLaunchKernelGGL(k_attmem, dim3(64, 4), dim3(128), 0, stream, attnm, feat_m, attm);
    hipLaunchKernelGGL(k_final, dim3(8), dim3(512), 0, stream,
                       feat_b, attm, w_fc, b_fc, (float*)d_out);
}